// Round 3
// baseline (910.543 us; speedup 1.0000x reference)
//
#include <hip/hip_runtime.h>

// FeCAM Mahalanobis: out[b,c] = -(v_b - m_c)^T M_c (v_b - m_c)
// B=512, C=200, D=768. inv_covs symmetric per class.
// Strategy: per-class bf16 MFMA GEMM G = Diff * M_c (128x128 tiles, K=32 steps),
// epilogue row-dot with f32 diff, atomicAdd into out. XCD-grouped blocks so the
// 4 row-tiles sharing M_c rows land on one XCD's L2.

#define B_SZ 512
#define C_SZ 200
#define D_SZ 768
#define BM 128
#define BN 128
#define BK 32
#define LDT 40                  // padded LDS row stride in bf16 elems (80 B)
#define NK (D_SZ / BK)          // 24

typedef __bf16 bf16x8 __attribute__((ext_vector_type(8)));
typedef float  f32x4  __attribute__((ext_vector_type(4)));

// ---------------- prep: Tukey + L2 normalize; zero the output ----------------
__global__ __launch_bounds__(256)
void fecam_prep(const float* __restrict__ raw,
                const float* __restrict__ cmeans,
                float* __restrict__ v_out,
                float* __restrict__ m_out,
                float* __restrict__ out)
{
    const int blk = blockIdx.x;
    const int tid = threadIdx.x;
    if (blk >= B_SZ + C_SZ) {
        // zero out[] (harness poisons with 0xAA; we accumulate atomically)
        const int base = (blk - (B_SZ + C_SZ)) * 1024;
        #pragma unroll
        for (int i = 0; i < 4; ++i) {
            int idx = base + i * 256 + tid;
            if (idx < B_SZ * C_SZ) out[idx] = 0.0f;
        }
        return;
    }
    const bool is_feat = (blk < B_SZ);
    const float* src = is_feat ? (raw    + (size_t)blk          * D_SZ)
                               : (cmeans + (size_t)(blk - B_SZ) * D_SZ);
    float*       dst = is_feat ? (v_out  + (size_t)blk          * D_SZ)
                               : (m_out  + (size_t)(blk - B_SZ) * D_SZ);
    float vals[3];
    float ss = 0.0f;
    #pragma unroll
    for (int i = 0; i < 3; ++i) {
        float xx = src[tid + i * 256];
        if (is_feat) xx = copysignf(sqrtf(fabsf(xx)), xx);   // sign(x)*|x|^0.5
        vals[i] = xx;
        ss += xx * xx;
    }
    #pragma unroll
    for (int off = 32; off; off >>= 1) ss += __shfl_xor(ss, off);
    __shared__ float red[4];
    if ((tid & 63) == 0) red[tid >> 6] = ss;
    __syncthreads();
    const float tot = red[0] + red[1] + red[2] + red[3];
    const float inv = 1.0f / fmaxf(sqrtf(tot), 1e-12f);
    #pragma unroll
    for (int i = 0; i < 3; ++i) dst[tid + i * 256] = vals[i] * inv;
}

// ---------------- main: per-class fused GEMM + quadratic-form epilogue -------
__global__ __launch_bounds__(256, 2)
void fecam_mahal(const float* __restrict__ v,
                 const float* __restrict__ m,
                 const float* __restrict__ invc,
                 float* __restrict__ out)
{
    __shared__ __bf16 As[BM * LDT];   // diff tile [b_local][e]
    __shared__ __bf16 Bs[BN * LDT];   // M tile    [d_local][e]  (M symmetric)

    // Block decode with XCD grouping: presume XCD = blockIdx % 8.
    // pair p = (class c, d-tile dt); all 4 b-row-tiles of p sit on one XCD.
    const int rr = blockIdx.x;
    const int x  = rr & 7;          // xcd slot
    const int t  = rr >> 3;         // 0..599
    const int rb = t & 3;           // b row-tile 0..3
    const int pg = t >> 2;          // 0..149
    const int p  = pg * 8 + x;      // pair 0..1199
    const int c  = p / 6;
    const int dt = p - c * 6;
    const int b0 = rb * BM;
    const int d0 = dt * BN;

    const int tid = threadIdx.x;
    const int row = tid >> 1;           // 0..127 : LDS tile row this thread stages
    const int eh  = (tid & 1) * 16;     // e-half within BK=32

    const float* vsrc = v    + (size_t)(b0 + row) * D_SZ + eh;
    const float* msrc = m    + (size_t)c * D_SZ + eh;
    const float* bsrc = invc + (size_t)c * D_SZ * D_SZ + (size_t)(d0 + row) * D_SZ + eh;

    const int lane = tid & 63;
    const int w    = tid >> 6;
    const int wr   = w >> 1;            // wave row (b 64-block)
    const int wc   = w & 1;             // wave col (d 64-block)
    const int l15  = lane & 15;
    const int g    = lane >> 4;

    f32x4 acc[4][4] = {};
    float4 va[4], vm[4], vb[4];

    #define LOADS(kk) do {                                                  \
        const int e0_ = (kk) * BK;                                          \
        _Pragma("unroll")                                                   \
        for (int i_ = 0; i_ < 4; ++i_) {                                    \
            va[i_] = *(const float4*)(vsrc + e0_ + i_ * 4);                 \
            vm[i_] = *(const float4*)(msrc + e0_ + i_ * 4);                 \
            vb[i_] = *(const float4*)(bsrc + e0_ + i_ * 4);                 \
        }                                                                   \
    } while (0)

    LOADS(0);

    for (int k = 0; k < NK; ++k) {
        if (k) __syncthreads();            // prior tile fully consumed
        {   // convert staged regs -> bf16, write LDS
            float af[16], bq[16];
            #pragma unroll
            for (int i = 0; i < 4; ++i) {
                af[i*4+0] = va[i].x - vm[i].x;  af[i*4+1] = va[i].y - vm[i].y;
                af[i*4+2] = va[i].z - vm[i].z;  af[i*4+3] = va[i].w - vm[i].w;
                bq[i*4+0] = vb[i].x; bq[i*4+1] = vb[i].y;
                bq[i*4+2] = vb[i].z; bq[i*4+3] = vb[i].w;
            }
            bf16x8 pa0, pa1, pb0, pb1;
            #pragma unroll
            for (int i = 0; i < 8; ++i) {
                pa0[i] = (__bf16)af[i];   pa1[i] = (__bf16)af[8 + i];
                pb0[i] = (__bf16)bq[i];   pb1[i] = (__bf16)bq[8 + i];
            }
            *(bf16x8*)&As[row * LDT + eh]     = pa0;
            *(bf16x8*)&As[row * LDT + eh + 8] = pa1;
            *(bf16x8*)&Bs[row * LDT + eh]     = pb0;
            *(bf16x8*)&Bs[row * LDT + eh + 8] = pb1;
        }
        __syncthreads();
        if (k + 1 < NK) LOADS(k + 1);      // prefetch flies under the MFMAs

        bf16x8 afr[4], bfr[4];
        #pragma unroll
        for (int mm = 0; mm < 4; ++mm)
            afr[mm] = *(const bf16x8*)&As[(wr*64 + mm*16 + l15) * LDT + g*8];
        #pragma unroll
        for (int nn = 0; nn < 4; ++nn)
            bfr[nn] = *(const bf16x8*)&Bs[(wc*64 + nn*16 + l15) * LDT + g*8];
        #pragma unroll
        for (int mm = 0; mm < 4; ++mm) {
            #pragma unroll
            for (int nn = 0; nn < 4; ++nn)
                acc[mm][nn] = __builtin_amdgcn_mfma_f32_16x16x32_bf16(
                    afr[mm], bfr[nn], acc[mm][nn], 0, 0, 0);
        }
    }
    #undef LOADS

    // Epilogue: out[b,c] -= sum_d G[b,d] * diff[b,d] over this WG's d-window.
    // C/D frag map (verified m89/m91): col = lane&15, row = (lane>>4)*4 + reg.
    const int based = d0 + wc * 64 + l15;
    float md[4];
    #pragma unroll
    for (int nn = 0; nn < 4; ++nn) md[nn] = m[(size_t)c * D_SZ + based + nn * 16];
    #pragma unroll
    for (int mm = 0; mm < 4; ++mm) {
        #pragma unroll
        for (int j = 0; j < 4; ++j) {
            const int b = b0 + wr * 64 + mm * 16 + g * 4 + j;
            float s = 0.0f;
            #pragma unroll
            for (int nn = 0; nn < 4; ++nn) {
                const float dv = v[(size_t)b * D_SZ + based + nn * 16] - md[nn];
                s += acc[mm][nn][j] * dv;
            }
            // reduce over the 16 lanes (same b, 16 d-columns)
            s += __shfl_xor(s, 1);
            s += __shfl_xor(s, 2);
            s += __shfl_xor(s, 4);
            s += __shfl_xor(s, 8);
            if (l15 == 0) atomicAdd(&out[(size_t)b * C_SZ + c], -s);
        }
    }
}

extern "C" void kernel_launch(void* const* d_in, const int* in_sizes, int n_in,
                              void* d_out, int out_size, void* d_ws, size_t ws_size,
                              hipStream_t stream)
{
    const float* raw    = (const float*)d_in[0];   // [512,768]
    const float* cmeans = (const float*)d_in[1];   // [200,768]
    const float* invc   = (const float*)d_in[2];   // [200,768,768]
    float* out = (float*)d_out;                    // [512,200]

    float* v  = (float*)d_ws;                      // 512*768 f32
    float* mn = v + (size_t)B_SZ * D_SZ;           // 200*768 f32

    // 712 norm blocks + 100 zeroing blocks (100*1024 == 512*200)
    fecam_prep<<<B_SZ + C_SZ + 100, 256, 0, stream>>>(raw, cmeans, v, mn, out);
    fecam_mahal<<<(C_SZ * 6) * 4, 256, 0, stream>>>(v, mn, invc, out);
}

// Round 4
// 876.339 us; speedup vs baseline: 1.0390x; 1.0390x over previous
//
#include <hip/hip_runtime.h>

// FeCAM Mahalanobis: out[b,c] = -(v_b - m_c)^T M_c (v_b - m_c),  B=512,C=200,D=768
// Decomposition: out = -vMv + 2vMm - mMm. GEMM G = V_bf16 * M_c (A class-independent,
// staged via global_load_lds from pre-tiled V; B reg-staged f32->bf16 with post-barrier
// issue / pre-barrier consume so no HBM load is barrier-drained). s_c = mMm via VALU
// FMA during B staging. Epilogue: out += sum_d G*(2m - v) - s_part, atomicAdd.

#define B_SZ 512
#define C_SZ 200
#define D_SZ 768
#define NK   24            // 768 / 32

typedef __bf16 bf16x8 __attribute__((ext_vector_type(8)));
typedef float  f32x4  __attribute__((ext_vector_type(4)));

__device__ __forceinline__ void gl16(const __bf16* g, __bf16* l) {
    __builtin_amdgcn_global_load_lds(
        (const __attribute__((address_space(1))) void*)g,
        (__attribute__((address_space(3))) void*)l, 16, 0, 0);
}

// ---------------- prep: Tukey+normalize -> v f32, m f32, V tiled bf16; zero out ----
__global__ __launch_bounds__(256)
void fecam_prep(const float* __restrict__ raw, const float* __restrict__ cmeans,
                float* __restrict__ v_out, float* __restrict__ m_out,
                __bf16* __restrict__ vt, float* __restrict__ out)
{
    const int blk = blockIdx.x;
    const int tid = threadIdx.x;
    if (blk >= B_SZ + C_SZ) {
        const int base = (blk - (B_SZ + C_SZ)) * 1024;
        #pragma unroll
        for (int i = 0; i < 4; ++i) {
            int idx = base + i * 256 + tid;
            if (idx < B_SZ * C_SZ) out[idx] = 0.0f;
        }
        return;
    }
    const bool isf = (blk < B_SZ);
    const float* src = isf ? raw + (size_t)blk * D_SZ
                           : cmeans + (size_t)(blk - B_SZ) * D_SZ;
    float vals[3]; float ss = 0.f;
    #pragma unroll
    for (int i = 0; i < 3; ++i) {
        float xx = src[tid + i * 256];
        if (isf) xx = copysignf(sqrtf(fabsf(xx)), xx);   // sign(x)*|x|^0.5
        vals[i] = xx; ss += xx * xx;
    }
    #pragma unroll
    for (int off = 32; off; off >>= 1) ss += __shfl_xor(ss, off);
    __shared__ float red[4];
    if ((tid & 63) == 0) red[tid >> 6] = ss;
    __syncthreads();
    const float inv = 1.0f / fmaxf(sqrtf(red[0] + red[1] + red[2] + red[3]), 1e-12f);
    if (isf) {
        const int b = blk;
        #pragma unroll
        for (int i = 0; i < 3; ++i) {
            const int e = tid + i * 256;
            const float val = vals[i] * inv;
            v_out[(size_t)b * D_SZ + e] = val;
            // tiled g-major layout: [bt][kt][g][row][j]
            const int idx = ((b >> 7) * NK + (e >> 5)) * 4096
                          + ((e >> 3) & 3) * 1024 + (b & 127) * 8 + (e & 7);
            vt[idx] = (__bf16)val;
        }
    } else {
        float* dst = m_out + (size_t)(blk - B_SZ) * D_SZ;
        #pragma unroll
        for (int i = 0; i < 3; ++i) dst[tid + i * 256] = vals[i] * inv;
    }
}

// ---------------- main --------------------------------------------------------------
__global__ __launch_bounds__(256, 2)
void fecam_mahal(const float* __restrict__ v, const float* __restrict__ m,
                 const __bf16* __restrict__ vt, const float* __restrict__ invc,
                 float* __restrict__ out)
{
    __shared__ __bf16 As[2][4096];   // [g][row][8] g-major, dbuf
    __shared__ __bf16 Bs[2][4096];
    __shared__ float  ms[D_SZ];
    __shared__ float  reds[4];

    // XCD-grouped decode: 4 b-row-tiles of one (c,dt) share an XCD's L2.
    const int rr = blockIdx.x;
    const int x  = rr & 7, tt = rr >> 3;
    const int rb = tt & 3, pg = tt >> 2;
    const int p  = pg * 8 + x;
    const int c  = p / 6, dt = p - c * 6;
    const int b0 = rb * 128, d0 = dt * 128;

    const int tid = threadIdx.x;
    const int lane = tid & 63, w = tid >> 6;
    const int wr = w >> 1, wc = w & 1;
    const int l15 = lane & 15, g = lane >> 4;
    const int drow = tid >> 1, eh = tid & 1;     // B staging role

    const float*  bsrc  = invc + (size_t)c * D_SZ * D_SZ + (size_t)(d0 + drow) * D_SZ + eh * 16;
    const __bf16* atile = vt + (size_t)rb * NK * 4096 + tid * 8;
    const float*  mrow  = m + (size_t)c * D_SZ;

    ms[tid]       = mrow[tid];
    ms[tid + 256] = mrow[tid + 256];
    ms[tid + 512] = mrow[tid + 512];

    float4 vb[4];
    float  sacc = 0.f;
    f32x4  acc[4][4] = {};

    auto issueB = [&](int kk) {
        const float* s = bsrc + kk * 32;
        vb[0] = *(const float4*)(s);
        vb[1] = *(const float4*)(s + 4);
        vb[2] = *(const float4*)(s + 8);
        vb[3] = *(const float4*)(s + 12);
    };
    auto gloadA = [&](int kk, int buf) {
        const __bf16* s = atile + kk * 4096;
        gl16(s,        &As[buf][tid * 8]);
        gl16(s + 2048, &As[buf][tid * 8 + 2048]);
    };
    auto writeB = [&](int buf, int kk) {
        float f[16];
        #pragma unroll
        for (int i = 0; i < 4; ++i) {
            f[i*4+0] = vb[i].x; f[i*4+1] = vb[i].y;
            f[i*4+2] = vb[i].z; f[i*4+3] = vb[i].w;
        }
        const float* mse = &ms[kk * 32 + eh * 16];
        float sl = 0.f;
        #pragma unroll
        for (int i = 0; i < 16; ++i) sl += f[i] * mse[i];   // s_c partial (f32 exact)
        sacc += sl;
        bf16x8 p0, p1;
        #pragma unroll
        for (int i = 0; i < 8; ++i) { p0[i] = (__bf16)f[i]; p1[i] = (__bf16)f[8+i]; }
        *(bf16x8*)&Bs[buf][(eh*2 + 0) * 1024 + drow * 8] = p0;
        *(bf16x8*)&Bs[buf][(eh*2 + 1) * 1024 + drow * 8] = p1;
    };
    auto mfmaPhase = [&](int buf) {
        bf16x8 afr[4], bfr[4];
        #pragma unroll
        for (int mm = 0; mm < 4; ++mm)
            afr[mm] = *(const bf16x8*)&As[buf][g * 1024 + (wr*64 + mm*16 + l15) * 8];
        #pragma unroll
        for (int nn = 0; nn < 4; ++nn)
            bfr[nn] = *(const bf16x8*)&Bs[buf][g * 1024 + (wc*64 + nn*16 + l15) * 8];
        #pragma unroll
        for (int mm = 0; mm < 4; ++mm)
            #pragma unroll
            for (int nn = 0; nn < 4; ++nn)
                acc[mm][nn] = __builtin_amdgcn_mfma_f32_16x16x32_bf16(
                    afr[mm], bfr[nn], acc[mm][nn], 0, 0, 0);
    };

    // prologue (one-time latency hit, amortized over 24 iters)
    issueB(0);
    gloadA(0, 0);
    __syncthreads();            // ms visible; vb0 + gloadA0 drained
    writeB(0, 0);
    __syncthreads();
    issueB(1);

    int cur = 0;
    for (int k = 0; k < NK; ++k) {
        if (k + 1 < NK) gloadA(k + 1, cur ^ 1);   // L2-hot, drained at this iter's barrier
        mfmaPhase(cur);
        if (k + 1 < NK) writeB(cur ^ 1, k + 1);   // exact-waits vb (aged one full phase)
        if (k + 1 < NK) __syncthreads();
        if (k + 2 < NK) issueB(k + 2);            // post-barrier issue: never drained
        cur ^= 1;
    }

    // s_c partial reduce (this block's d-window, all e)
    float sthr = ms[d0 + drow] * sacc;
    #pragma unroll
    for (int off = 1; off < 64; off <<= 1) sthr += __shfl_xor(sthr, off);
    if (lane == 0) reds[w] = sthr;
    __syncthreads();
    const float s_part = reds[0] + reds[1] + reds[2] + reds[3];

    // out[b,c] += sum_d G[b,d]*(2 m[d] - v[b,d]) - s_part   (C/D map m89/m91)
    const int dbase = d0 + wc * 64 + l15;
    float md2[4];
    #pragma unroll
    for (int nn = 0; nn < 4; ++nn) md2[nn] = 2.0f * ms[dbase - d0 + d0 + nn * 16];
    #pragma unroll
    for (int mm = 0; mm < 4; ++mm) {
        #pragma unroll
        for (int j = 0; j < 4; ++j) {
            const int b = b0 + wr * 64 + mm * 16 + g * 4 + j;
            const float* vrow = v + (size_t)b * D_SZ + dbase;
            float val = 0.f;
            #pragma unroll
            for (int nn = 0; nn < 4; ++nn)
                val += acc[mm][nn][j] * (md2[nn] - vrow[nn * 16]);
            val += __shfl_xor(val, 1);
            val += __shfl_xor(val, 2);
            val += __shfl_xor(val, 4);
            val += __shfl_xor(val, 8);
            if (l15 == 0)
                atomicAdd(&out[(size_t)b * C_SZ + c], (wc == 0) ? (val - s_part) : val);
        }
    }
}

extern "C" void kernel_launch(void* const* d_in, const int* in_sizes, int n_in,
                              void* d_out, int out_size, void* d_ws, size_t ws_size,
                              hipStream_t stream)
{
    const float* raw    = (const float*)d_in[0];   // [512,768]
    const float* cmeans = (const float*)d_in[1];   // [200,768]
    const float* invc   = (const float*)d_in[2];   // [200,768,768]
    float* out = (float*)d_out;                    // [512,200]

    float*  v  = (float*)d_ws;                          // 512*768 f32
    float*  mn = v + (size_t)B_SZ * D_SZ;               // 200*768 f32
    __bf16* vt = (__bf16*)(mn + (size_t)C_SZ * D_SZ);   // 512*768 bf16, tiled

    fecam_prep<<<B_SZ + C_SZ + 100, 256, 0, stream>>>(raw, cmeans, v, mn, vt, out);
    fecam_mahal<<<4800, 256, 0, stream>>>(v, mn, vt, invc, out);
}

// Round 5
// 805.024 us; speedup vs baseline: 1.1311x; 1.0886x over previous
//
#include <hip/hip_runtime.h>

// FeCAM Mahalanobis: out[b,c] = -(v_b - m_c)^T M_c (v_b - m_c),  B=512,C=200,D=768
// out = -vMv + 2vMm - mMm. One 512-thread block per (c, d-tile): BM=512 x BN=128.
// B-tile (M_c rows, f32) staged via global_load_lds 2-deep into 3 XOR-swizzled LDS
// buffers (swizzle applied on the per-lane GLOBAL source; LDS dest linear; reads
// apply matching XOR). A (pre-tiled bf16 V) via global_load_lds, double-buffered.
// Raw s_barrier + constant s_waitcnt vmcnt(8) -- prefetch never drained to 0.

#define B_SZ 512
#define C_SZ 200
#define D_SZ 768
#define NK   24
#define DD   (D_SZ * D_SZ)

typedef __bf16 bf16x8 __attribute__((ext_vector_type(8)));
typedef float  f32x4  __attribute__((ext_vector_type(4)));

__device__ __forceinline__ void gl16(const void* g, void* l) {
    __builtin_amdgcn_global_load_lds(
        (const __attribute__((address_space(1))) void*)g,
        (__attribute__((address_space(3))) void*)l, 16, 0, 0);
}

// ---------------- prep: Tukey + L2 normalize; v f32, m f32, V tiled bf16; zero out --
__global__ __launch_bounds__(256)
void fecam_prep(const float* __restrict__ raw, const float* __restrict__ cmeans,
                float* __restrict__ v_out, float* __restrict__ m_out,
                __bf16* __restrict__ vt, float* __restrict__ out)
{
    const int blk = blockIdx.x;
    const int tid = threadIdx.x;
    if (blk >= B_SZ + C_SZ) {
        const int base = (blk - (B_SZ + C_SZ)) * 1024;
        #pragma unroll
        for (int i = 0; i < 4; ++i) {
            int idx = base + i * 256 + tid;
            if (idx < B_SZ * C_SZ) out[idx] = 0.0f;
        }
        return;
    }
    const bool isf = (blk < B_SZ);
    const float* src = isf ? raw + (size_t)blk * D_SZ
                           : cmeans + (size_t)(blk - B_SZ) * D_SZ;
    float vals[3]; float ss = 0.f;
    #pragma unroll
    for (int i = 0; i < 3; ++i) {
        float xx = src[tid + i * 256];
        if (isf) xx = copysignf(sqrtf(fabsf(xx)), xx);   // sign(x)*|x|^0.5
        vals[i] = xx; ss += xx * xx;
    }
    #pragma unroll
    for (int off = 32; off; off >>= 1) ss += __shfl_xor(ss, off);
    __shared__ float red[4];
    if ((tid & 63) == 0) red[tid >> 6] = ss;
    __syncthreads();
    const float inv = 1.0f / fmaxf(sqrtf(red[0] + red[1] + red[2] + red[3]), 1e-12f);
    if (isf) {
        const int b = blk;
        #pragma unroll
        for (int i = 0; i < 3; ++i) {
            const int e = tid + i * 256;
            const float val = vals[i] * inv;
            v_out[(size_t)b * D_SZ + e] = val;
            // per-k-tile [g][row 0..511][8] layout: 16384 elems per k-tile
            const int idx = (e >> 5) * 16384 + ((e >> 3) & 3) * 4096 + b * 8 + (e & 7);
            vt[idx] = (__bf16)val;
        }
    } else {
        float* dst = m_out + (size_t)(blk - B_SZ) * D_SZ;
        #pragma unroll
        for (int i = 0; i < 3; ++i) dst[tid + i * 256] = vals[i] * inv;
    }
}

// ---------------- main ---------------------------------------------------------------
__global__ __launch_bounds__(512, 2)
void fecam_mahal(const float* __restrict__ v, const float* __restrict__ m,
                 const __bf16* __restrict__ vt, const float* __restrict__ invc,
                 float* __restrict__ out)
{
    __shared__ __bf16 As[2][16384];   // 2 x 32KB  [g][row][8] bf16
    __shared__ float  Bs[3][4096];    // 3 x 16KB  128 rows x 128B, XOR-swizzled
    __shared__ float  ms[D_SZ];
    __shared__ float  reds[2];

    const int bid = blockIdx.x;
    const int c   = bid / 6;
    const int dt  = bid - c * 6;
    const int d0  = dt * 128;

    const int tid  = threadIdx.x;
    const int lane = tid & 63;
    const int w    = tid >> 6;        // 0..7
    const int wr   = w >> 1;          // 0..3 : 128-row group
    const int wc   = w & 1;           // 0..1 : 64-col group
    const int l15  = lane & 15;
    const int g    = lane >> 4;

    ms[tid] = m[(size_t)c * D_SZ + tid];
    if (tid < 256) ms[512 + tid] = m[(size_t)c * D_SZ + 512 + tid];
    __syncthreads();                  // drains vmcnt too -- before any gl16

    // B staging: wave w, instr i: rows w*16+i*8+(lane>>3); lane 16B slot (lane&7),
    // source pre-XOR'd: ebyte = ((lane&7) ^ (lane>>3)) << 4
    const int brow = w * 16 + (lane >> 3);
    const int bel  = (((lane & 7) ^ ((lane >> 3) & 7)) << 4) >> 2;
    const float* bsrc = invc + (size_t)c * DD + (size_t)(d0 + brow) * D_SZ + bel;
    // A staging: wave w, instr i: source elems w*2048 + i*512 + lane*8
    const __bf16* asrc = vt + w * 2048 + lane * 8;

    auto issueA = [&](int kk, int buf) {
        const __bf16* s = asrc + kk * 16384;
        char* d = (char*)&As[buf][0] + w * 4096;
        #pragma unroll
        for (int i = 0; i < 4; ++i) gl16(s + i * 512, d + i * 1024);
    };
    auto issueB = [&](int kk, int buf) {
        const float* s = bsrc + kk * 32;
        char* d = (char*)&Bs[buf][0] + w * 2048;
        gl16(s, d);
        gl16(s + 8 * D_SZ, d + 1024);
    };

    f32x4 acc[8][4] = {};
    float sacc0 = 0.f, sacc1 = 0.f, sacc2 = 0.f, sacc3 = 0.f;

    issueB(0, 0); issueA(0, 0); issueB(1, 1);          // 8 outstanding / wave

    for (int k = 0; k < NK; ++k) {
        __builtin_amdgcn_s_barrier();                  // all waves done reading k-1 bufs
        const int ka = (k + 1 < NK) ? k + 1 : NK - 1;
        issueA(ka, (k + 1) & 1);
        const int kb = (k + 2 < NK) ? k + 2 : NK - 1;
        issueB(kb, (k + 2) % 3);
        asm volatile("s_waitcnt vmcnt(8)" ::: "memory");  // own A(k),B(k) landed
        __builtin_amdgcn_s_barrier();                  // everyone's tile-k DMA published
        __builtin_amdgcn_sched_barrier(0);

        // B frags: f32 read (XOR-swizzled) -> bf16; s_c partials on wr==0 waves
        const float* bb = &Bs[k % 3][0];
        float bme[8];
        if (w < 2) {
            #pragma unroll
            for (int i = 0; i < 8; ++i) bme[i] = ms[k * 32 + g * 8 + i];
        }
        bf16x8 bfr[4];
        #pragma unroll
        for (int nn = 0; nn < 4; ++nn) {
            const int col = wc * 64 + nn * 16 + l15;
            const int sw  = (col & 7) << 4;
            const int o0  = (col * 128 + ((g * 32) ^ sw)) >> 2;
            const int o1  = (col * 128 + ((g * 32 + 16) ^ sw)) >> 2;
            const f32x4 b0 = *(const f32x4*)(bb + o0);
            const f32x4 b1 = *(const f32x4*)(bb + o1);
            bf16x8 t;
            t[0] = (__bf16)b0[0]; t[1] = (__bf16)b0[1];
            t[2] = (__bf16)b0[2]; t[3] = (__bf16)b0[3];
            t[4] = (__bf16)b1[0]; t[5] = (__bf16)b1[1];
            t[6] = (__bf16)b1[2]; t[7] = (__bf16)b1[3];
            bfr[nn] = t;
            if (w < 2) {
                const float s = b0[0]*bme[0] + b0[1]*bme[1] + b0[2]*bme[2] + b0[3]*bme[3]
                              + b1[0]*bme[4] + b1[1]*bme[5] + b1[2]*bme[6] + b1[3]*bme[7];
                if      (nn == 0) sacc0 += s;
                else if (nn == 1) sacc1 += s;
                else if (nn == 2) sacc2 += s;
                else              sacc3 += s;
            }
        }
        // A frags + MFMA
        const __bf16* ab = &As[k & 1][0];
        #pragma unroll
        for (int mm = 0; mm < 8; ++mm) {
            const int row = wr * 128 + mm * 16 + l15;
            const bf16x8 af = *(const bf16x8*)(ab + g * 4096 + row * 8);
            #pragma unroll
            for (int nn = 0; nn < 4; ++nn)
                acc[mm][nn] = __builtin_amdgcn_mfma_f32_16x16x32_bf16(
                    af, bfr[nn], acc[mm][nn], 0, 0, 0);
        }
    }

    // s_c partial (this block's 128-col window, full e) from wr==0 waves
    if (w < 2) {
        const int cb = d0 + wc * 64 + l15;
        float s = ms[cb] * sacc0 + ms[cb + 16] * sacc1
                + ms[cb + 32] * sacc2 + ms[cb + 48] * sacc3;
        #pragma unroll
        for (int off = 1; off < 64; off <<= 1) s += __shfl_xor(s, off);
        if (lane == 0) reds[w] = s;
    }
    __syncthreads();                   // also drains leftover prefetch DMA
    const float s_part = reds[0] + reds[1];

    // out[b,c] += sum_d G[b,d]*(2 m[d] - v[b,d]) - s_part   (C/D map: col=l15, row=g*4+reg)
    const int dbase = d0 + wc * 64 + l15;
    float md2[4];
    #pragma unroll
    for (int nn = 0; nn < 4; ++nn) md2[nn] = 2.0f * ms[dbase + nn * 16];
    #pragma unroll
    for (int mm = 0; mm < 8; ++mm) {
        #pragma unroll
        for (int j = 0; j < 4; ++j) {
            const int b = wr * 128 + mm * 16 + g * 4 + j;
            const float* vrow = v + (size_t)b * D_SZ + dbase;
            float val = acc[mm][0][j] * (md2[0] - vrow[0])
                      + acc[mm][1][j] * (md2[1] - vrow[16])
                      + acc[mm][2][j] * (md2[2] - vrow[32])
                      + acc[mm][3][j] * (md2[3] - vrow[48]);
            val += __shfl_xor(val, 1);
            val += __shfl_xor(val, 2);
            val += __shfl_xor(val, 4);
            val += __shfl_xor(val, 8);
            if (l15 == 0)
                atomicAdd(&out[(size_t)b * C_SZ + c], (wc == 0) ? (val - s_part) : val);
        }
    }
}

extern "C" void kernel_launch(void* const* d_in, const int* in_sizes, int n_in,
                              void* d_out, int out_size, void* d_ws, size_t ws_size,
                              hipStream_t stream)
{
    const float* raw    = (const float*)d_in[0];   // [512,768]
    const float* cmeans = (const float*)d_in[1];   // [200,768]
    const float* invc   = (const float*)d_in[2];   // [200,768,768]
    float* out = (float*)d_out;                    // [512,200]

    float*  vf = (float*)d_ws;                          // 512*768 f32
    float*  mn = vf + (size_t)B_SZ * D_SZ;              // 200*768 f32
    __bf16* vt = (__bf16*)(mn + (size_t)C_SZ * D_SZ);   // 512*768 bf16, k-tiled

    fecam_prep<<<B_SZ + C_SZ + 100, 256, 0, stream>>>(raw, cmeans, vf, mn, vt, out);
    fecam_mahal<<<C_SZ * 6, 512, 0, stream>>>(vf, mn, vt, invc, out);
}